// Round 8
// baseline (363.780 us; speedup 1.0000x reference)
//
#include <hip/hip_runtime.h>

#define K_CODES 512
#define DIM 64
#define HW 1024
#define NVEC 65536

// Output offsets (flat concat, reference return order)
#define O0 0             // loss (1)
#define O1 1             // out_q NCHW (4194304) -- xT scratch until k_q
#define O2 4194305       // perplexity (1)
#define O3 4194306       // idx as float (65536)
#define O4 4259842       // new_cs (512)
#define O5 4260354       // new_ema_w (32768)
#define O6 4293122       // new_embedding (32768)

// ws float-offset layout (~730 KB)
#define WS_LOSS 0        // 512 per-block loss partials
#define WS_EE   1024     // 512 ||e||^2
#define WS_IDX  1536     // 65536 int: (rank<<9)|code
#define WS_GCNT 67072    // 512 int counts
#define WS_BASE 67584    // 512 int segment bases
#define WS_VL   68096    // 65536 int vlist (vector ids sorted by code)
#define WS_BP   133632   // 98304 bf16 B-pack (MFMA-frag order)
#define XSS     65       // odd LDS row stride -> <=2-way bank aliasing

typedef __bf16 bf16x8 __attribute__((ext_vector_type(8)));
typedef float  f32x4  __attribute__((ext_vector_type(4)));

__global__ void k0_init(const float* __restrict__ emb, float* __restrict__ wsf) {
    const int b = blockIdx.x, t = threadIdx.x;
    if (b < 2) {
        int k = b * 256 + t;                             // 0..511
        const float* e = emb + k * DIM;
        float s = 0.0f;
        #pragma unroll
        for (int c = 0; c < DIM; ++c) s += e[c] * e[c];
        wsf[WS_EE + k] = s;                              // ||e_k||^2
    } else if (b == 2) {
        int* g = (int*)(wsf + WS_GCNT);
        g[t] = 0; g[t + 256] = 0;                        // zero counts (ws is poisoned)
    } else {
        // Pack bf16 3-way split of (-2*e) into MFMA B-fragment order:
        // frag(s, ntg, ks): lane l holds B^T[code = ntg*16 + (l&15)][c = ks*32 + (l>>4)*8 + j]
        int g = (b - 3) * 256 + t;                       // 0..98303
        int j    = g & 7;
        int lane = (g >> 3) & 63;
        int ks   = (g >> 9) & 1;
        int rest = g >> 10;                              // 0..95
        int ntg  = rest & 31;
        int s    = rest >> 5;                            // split 0..2
        int code = ntg * 16 + (lane & 15);
        int c    = ks * 32 + (lane >> 4) * 8 + j;
        float v = -2.0f * emb[code * DIM + c];
        __bf16 h0 = (__bf16)v;  float r1 = v  - (float)h0;
        __bf16 h1 = (__bf16)r1; float r2 = r1 - (float)h1;
        __bf16 hv = (s == 0) ? h0 : (s == 1 ? h1 : (__bf16)r2);
        ((__bf16*)(wsf + WS_BP))[g] = hv;
    }
}

// Block: 512 threads = 8 waves; 128 vectors x 512 codes per block. GEMM + argmin,
// rank assignment (global int atomic), xT flush to O1 scratch.
__global__ __launch_bounds__(512, 2)
void k1_main(const float* __restrict__ in, const float* __restrict__ emb,
             float* __restrict__ out, float* __restrict__ wsf) {
    __shared__ float xs[128 * XSS];
    __shared__ float pmin[4][128];
    __shared__ int   pidx[4][128];
    __shared__ float xxs[128];
    __shared__ float lossp[2];

    const int t    = threadIdx.x;
    const int lane = t & 63;
    const int wave = t >> 6;
    const int mi2  = wave & 1;         // m half (64 vectors)
    const int ni2  = wave >> 1;        // n quarter (128 codes)
    const int col  = lane & 15;
    const int quad = lane >> 4;

    const int blk     = blockIdx.x;
    const int n_img   = blk >> 3;
    const int hw_base = (blk & 7) * 128;
    const float* xbase = in + n_img * (DIM * HW) + hw_base;

    #pragma unroll
    for (int rep = 0; rep < 16; ++rep) {
        int e = rep * 512 + t;
        int c = e >> 7, h0 = e & 127;
        xs[h0 * XSS + c] = xbase[c * HW + h0];
    }

    f32x4 acc[4][8];
    #pragma unroll
    for (int nt = 0; nt < 8; ++nt) {
        float eev = wsf[WS_EE + ni2 * 128 + nt * 16 + col];
        #pragma unroll
        for (int mi = 0; mi < 4; ++mi) {
            acc[mi][nt][0] = eev; acc[mi][nt][1] = eev;
            acc[mi][nt][2] = eev; acc[mi][nt][3] = eev;
        }
    }

    __syncthreads();

    if (t < 128) {
        float s = 0.0f;
        #pragma unroll
        for (int c = 0; c < DIM; ++c) { float v = xs[t * XSS + c]; s += v * v; }
        xxs[t] = s;
    }

    const bf16x8* bp8 = (const bf16x8*)(wsf + WS_BP);

    #pragma unroll
    for (int ks = 0; ks < 2; ++ks) {
        bf16x8 A0[4], A1[4], A2[4];
        #pragma unroll
        for (int mi = 0; mi < 4; ++mi) {
            const float* src = &xs[(mi2 * 64 + mi * 16 + col) * XSS + ks * 32 + quad * 8];
            #pragma unroll
            for (int j = 0; j < 8; ++j) {
                float v = src[j];
                __bf16 h0 = (__bf16)v;  float r1 = v  - (float)h0;
                __bf16 h1 = (__bf16)r1; float r2 = r1 - (float)h1;
                A0[mi][j] = h0; A1[mi][j] = h1; A2[mi][j] = (__bf16)r2;
            }
        }
        #pragma unroll
        for (int s = 0; s < 3; ++s) {
            bf16x8 Bv[8];
            #pragma unroll
            for (int nt = 0; nt < 8; ++nt)
                Bv[nt] = bp8[(((s * 32 + ni2 * 8 + nt) * 2 + ks) * 64) + lane];
            #pragma unroll
            for (int mi = 0; mi < 4; ++mi)
                #pragma unroll
                for (int nt = 0; nt < 8; ++nt)
                    acc[mi][nt] = __builtin_amdgcn_mfma_f32_16x16x32_bf16(A0[mi], Bv[nt], acc[mi][nt], 0, 0, 0);
            if (s < 2) {
                #pragma unroll
                for (int mi = 0; mi < 4; ++mi)
                    #pragma unroll
                    for (int nt = 0; nt < 8; ++nt)
                        acc[mi][nt] = __builtin_amdgcn_mfma_f32_16x16x32_bf16(A1[mi], Bv[nt], acc[mi][nt], 0, 0, 0);
            }
            if (s == 0) {
                #pragma unroll
                for (int mi = 0; mi < 4; ++mi)
                    #pragma unroll
                    for (int nt = 0; nt < 8; ++nt)
                        acc[mi][nt] = __builtin_amdgcn_mfma_f32_16x16x32_bf16(A2[mi], Bv[nt], acc[mi][nt], 0, 0, 0);
            }
        }
    }

    // Argmin. C layout: col(code) = lane&15, row(vector) = quad*4 + reg.
    #pragma unroll
    for (int mi = 0; mi < 4; ++mi) {
        #pragma unroll
        for (int r = 0; r < 4; ++r) {
            float v  = acc[mi][0][r];
            int   bi = ni2 * 128 + col;
            #pragma unroll
            for (int nt = 1; nt < 8; ++nt) {            // ascending codes, strict < = first-min
                float u  = acc[mi][nt][r];
                int   ui = ni2 * 128 + nt * 16 + col;
                if (u < v) { v = u; bi = ui; }
            }
            #pragma unroll
            for (int off = 1; off < 16; off <<= 1) {    // 16-lane butterfly, idx tie-break
                float ov = __shfl_xor(v, off);
                int   oi = __shfl_xor(bi, off);
                if (ov < v || (ov == v && oi < bi)) { v = ov; bi = oi; }
            }
            if (col == 0) {
                int row = mi2 * 64 + mi * 16 + quad * 4 + r;
                pmin[ni2][row] = v;
                pidx[ni2][row] = bi;
            }
        }
    }
    __syncthreads();

    if (t < 128) {
        float v = pmin[0][t]; int bi = pidx[0][t];
        #pragma unroll
        for (int q = 1; q < 4; ++q) {
            float u = pmin[q][t]; int ui = pidx[q][t];
            if (u < v) { v = u; bi = ui; }
        }
        out[O3 + blk * 128 + t] = (float)bi;
        int rk = atomicAdd((int*)(wsf + WS_GCNT) + bi, 1);      // rank within code
        ((int*)(wsf + WS_IDX))[blk * 128 + t] = (rk << 9) | bi; // packed
        float ld = v + xxs[t];                           // d_min = xx + (ee - 2<x,e>)
        #pragma unroll
        for (int off = 32; off > 0; off >>= 1) ld += __shfl_down(ld, off);
        if ((t & 63) == 0) lossp[t >> 6] = ld;
    }
    __syncthreads();
    if (t == 0) wsf[WS_LOSS + blk] = lossp[0] + lossp[1];

    // Flush xT rows (vector-major, 64 floats/row) into O1 scratch -- coalesced
    float* xq = out + O1 + blk * (128 * 64);
    #pragma unroll
    for (int rep = 0; rep < 16; ++rep) {
        int g = rep * 512 + t;
        int row = g >> 6, c = g & 63;
        xq[g] = xs[row * XSS + c];
    }
}

// Single block: prefix-sum counts -> base; new_cs + perplexity + loss (old k2a).
__global__ __launch_bounds__(512)
void k_pre(const float* __restrict__ ema_cs, float* __restrict__ out,
           float* __restrict__ wsf) {
    __shared__ float s1[512], s2[512], s3[512];
    __shared__ int   sc[512];
    const int t = threadIdx.x;
    const int* gcnt = (const int*)(wsf + WS_GCNT);
    int ci = gcnt[t];
    float c = (float)ci;
    float raw = 0.99f * ema_cs[t] + 0.01f * c;
    float p   = c * (1.0f / 65536.0f);
    s1[t] = raw;
    s2[t] = p * logf(p + 1e-10f);
    s3[t] = wsf[WS_LOSS + t];
    sc[t] = ci;
    __syncthreads();
    // inclusive Hillis-Steele scan on counts
    for (int off = 1; off < 512; off <<= 1) {
        int v = (t >= off) ? sc[t - off] : 0;
        __syncthreads();
        sc[t] += v;
        __syncthreads();
    }
    ((int*)(wsf + WS_BASE))[t] = sc[t] - ci;             // exclusive base
    for (int s = 256; s > 0; s >>= 1) {
        if (t < s) { s1[t] += s1[t + s]; s2[t] += s2[t + s]; s3[t] += s3[t + s]; }
        __syncthreads();
    }
    float n = s1[0];
    float smooth = (raw + 1e-5f) / (n + 512.0f * 1e-5f) * n;   // Laplace smoothing
    out[O4 + t] = smooth;
    if (t == 0) {
        out[O2] = expf(-s2[0]);
        out[O0] = 0.25f * s3[0] * (1.0f / 4194304.0f);         // BETA * mean
    }
}

// Build vlist: vector ids grouped by code (counting-sort placement).
__global__ __launch_bounds__(256)
void k_fill(float* __restrict__ wsf) {
    const int v = blockIdx.x * 256 + threadIdx.x;
    int comb = ((const int*)(wsf + WS_IDX))[v];
    int code = comb & 511, rk = comb >> 9;
    int pos  = ((const int*)(wsf + WS_BASE))[code] + rk;
    ((int*)(wsf + WS_VL))[pos] = v;
}

// One block per code: gather its contiguous segment of xT rows, sum in VGPRs,
// emit new_ema_w (O5) and new_embedding (O6) directly. No partials, no atomics.
__global__ __launch_bounds__(256)
void k_sum(const float* __restrict__ xT, const float* __restrict__ ema_w,
           float* __restrict__ out, const float* __restrict__ wsf) {
    __shared__ float sacc[4][64];
    const int t = threadIdx.x, lane = t & 63, w = t >> 6;
    const int k = blockIdx.x;
    const int cnt = ((const int*)(wsf + WS_GCNT))[k];
    const int b0  = ((const int*)(wsf + WS_BASE))[k];
    const int* vl = (const int*)(wsf + WS_VL) + b0;

    float a0 = 0.f, a1 = 0.f, a2 = 0.f, a3 = 0.f;
    for (int i = w * 4; i < cnt; i += 16) {              // 4 independent rows in flight
        int rem = cnt - i;
        int v0 = vl[i];
        a0 += xT[v0 * 64 + lane];
        if (rem > 1) { int v1 = vl[i + 1]; a1 += xT[v1 * 64 + lane]; }
        if (rem > 2) { int v2 = vl[i + 2]; a2 += xT[v2 * 64 + lane]; }
        if (rem > 3) { int v3 = vl[i + 3]; a3 += xT[v3 * 64 + lane]; }
    }
    sacc[w][lane] = (a0 + a1) + (a2 + a3);
    __syncthreads();
    if (w == 0) {
        float dw = (sacc[0][lane] + sacc[1][lane]) + (sacc[2][lane] + sacc[3][lane]);
        float wv = 0.99f * ema_w[k * 64 + lane] + 0.01f * dw;
        out[O5 + k * 64 + lane] = wv;
        out[O6 + k * 64 + lane] = wv / out[O4 + k];      // new_cs written by k_pre
    }
}

// Regenerate out_q into O1 from emb + idx (xT scratch consumed by k_sum).
__global__ __launch_bounds__(256, 4)
void k_q(const float* __restrict__ emb, const int* __restrict__ idxc,
         float* __restrict__ out) {
    const int t    = threadIdx.x;
    const int lane = t & 63;
    const int cg   = t >> 6;                 // c-group 0..3 (16 channels each)
    const int b    = blockIdx.x;
    const int n    = b >> 4;
    const int hw0  = (b & 15) * 64;

    int iv = idxc[n * HW + hw0 + lane] & 511;
    const f32x4* er = (const f32x4*)(emb + iv * DIM + cg * 16);   // 64B row chunk
    f32x4 e0 = er[0], e1 = er[1], e2 = er[2], e3 = er[3];
    float ev[16];
    #pragma unroll
    for (int j = 0; j < 4; ++j) { ev[j] = e0[j]; ev[4+j] = e1[j]; ev[8+j] = e2[j]; ev[12+j] = e3[j]; }

    float* ob = out + O1 + n * (DIM * HW) + hw0 + lane;
    #pragma unroll
    for (int j = 0; j < 16; ++j) ob[(cg * 16 + j) * HW] = ev[j];    // coalesced planes
}

extern "C" void kernel_launch(void* const* d_in, const int* in_sizes, int n_in,
                              void* d_out, int out_size, void* d_ws, size_t ws_size,
                              hipStream_t stream) {
    const float* in     = (const float*)d_in[0];   // inputs  (64,64,32,32) NCHW
    const float* emb    = (const float*)d_in[1];   // embedding (512,64)
    const float* ema_w  = (const float*)d_in[2];   // ema_w (512,64)
    const float* ema_cs = (const float*)d_in[3];   // ema_cluster_size (512)
    float* out = (float*)d_out;
    float* wsf = (float*)d_ws;
    const int* idxc = (const int*)(wsf + WS_IDX);

    hipLaunchKernelGGL(k0_init, dim3(387),  dim3(256), 0, stream, emb, wsf);
    hipLaunchKernelGGL(k1_main, dim3(512),  dim3(512), 0, stream, in, emb, out, wsf);
    hipLaunchKernelGGL(k_pre,   dim3(1),    dim3(512), 0, stream, ema_cs, out, wsf);
    hipLaunchKernelGGL(k_fill,  dim3(256),  dim3(256), 0, stream, wsf);
    hipLaunchKernelGGL(k_sum,   dim3(512),  dim3(256), 0, stream, out + O1, ema_w, out, wsf);
    hipLaunchKernelGGL(k_q,     dim3(1024), dim3(256), 0, stream, emb, idxc, out);
}